// Round 15
// baseline (542.940 us; speedup 1.0000x reference)
//
#include <hip/hip_runtime.h>

#define D 1024
#define HD 128
#define EA 8
#define EF 16
#define FH 512
#define MAXPOS 64
#define RNUM 129
#define RSTRIDE 132
#define SEQ 1024
#define NTOK 4096
#define NPAIR (NTOK * 2)
#define NPAD 8320          // NPAIR + 128 slack
#define LN_EPS 1e-5f
#define QSCALE 0.08838834764831845f
#define BSTR 32            // linear LDS row stride in bf16 elems (global_load_lds needs linear)
#define NSPL 2             // split-K splits (green structure)
#define NKV 4              // flash: KV splits (2 K-tiles each)

typedef __attribute__((ext_vector_type(8))) short bf16x8;
typedef __attribute__((ext_vector_type(4))) float f32x4;
typedef __attribute__((ext_vector_type(8))) unsigned short u16x8;

__device__ inline ushort f2b(float f) {
    union { float f; unsigned u; } v; v.f = f;
    unsigned r = (v.u + 0x7fffu + ((v.u >> 16) & 1u)) >> 16;
    return (ushort)r;
}
__device__ inline float b2f(ushort u) {
    union { unsigned u; float f; } v; v.u = (unsigned)u << 16; return v.f;
}

// async global->LDS, 16B per lane, dest = wave-uniform base + lane*16
__device__ __forceinline__ void gll(const void* g, void* l) {
    __builtin_amdgcn_global_load_lds((const __attribute__((address_space(1))) void*)g,
                                     (__attribute__((address_space(3))) void*)l, 16, 0, 0);
}
__device__ __forceinline__ void wait_vm0()  { asm volatile("s_waitcnt vmcnt(0)" ::: "memory"); }
__device__ __forceinline__ void wait_vm3()  { asm volatile("s_waitcnt vmcnt(3)" ::: "memory"); }
__device__ __forceinline__ void wait_vm8()  { asm volatile("s_waitcnt vmcnt(8)" ::: "memory"); }
__device__ __forceinline__ void wait_vm16() { asm volatile("s_waitcnt vmcnt(16)" ::: "memory"); }
__device__ __forceinline__ void bar() { __builtin_amdgcn_s_barrier(); }

// one double-buffer compute step: 64x128 tile, wave = 32x64
__device__ inline void mfma_step(const short* Asb, const short* Bsb,
                                 int wr, int wc, int m16, int q, f32x4 (&acc)[2][4]) {
    bf16x8 af[2], bfr[4];
#pragma unroll
    for (int i = 0; i < 2; i++) af[i] = *(const bf16x8*)&Asb[(wr + i * 16 + m16) * BSTR + q * 8];
#pragma unroll
    for (int j = 0; j < 4; j++) bfr[j] = *(const bf16x8*)&Bsb[(wc + j * 16 + m16) * BSTR + q * 8];
#pragma unroll
    for (int i = 0; i < 2; i++)
#pragma unroll
        for (int j = 0; j < 4; j++)
            acc[i][j] = __builtin_amdgcn_mfma_f32_16x16x32_bf16(af[i], bfr[j], acc[i][j], 0, 0, 0);
}

// depth-2 counted-vmcnt K-loop (T3/T4-lite).
#define KLOOP(NK, AP, BP0, BP1, STRIDE)                                          \
    gll(AP, &As[0][w * 512]); gll(BP0, &Bs[0][w * 1024]); gll(BP1, &Bs[0][w * 1024 + 512]); \
    gll(AP + STRIDE, &As[1][w * 512]); gll(BP0 + STRIDE, &Bs[1][w * 1024]);      \
    gll(BP1 + STRIDE, &Bs[1][w * 1024 + 512]);                                   \
    {                                                                            \
        int cur = 0;                                                             \
        for (int k = 0; k < NK; k++) {                                           \
            if (k < NK - 1) wait_vm3(); else wait_vm0();                         \
            bar();                                                               \
            mfma_step(As[cur], Bs[cur], wr, wc, m16, q, acc);                    \
            if (k + 2 < NK) {                                                    \
                bar();                                                           \
                gll(AP + (k + 2) * STRIDE, &As[cur][w * 512]);                   \
                gll(BP0 + (k + 2) * STRIDE, &Bs[cur][w * 1024]);                 \
                gll(BP1 + (k + 2) * STRIDE, &Bs[cur][w * 1024 + 512]);           \
            }                                                                    \
            cur ^= 1;                                                            \
        }                                                                        \
    }

// ---- LayerNorm + fused router (bit-exact r2-lineage router) + fused attn-bin count.
template <int E>
__global__ void ln_router_kernel(const float* __restrict__ x, const float* __restrict__ w,
                                 const float* __restrict__ b, const float* __restrict__ gw,
                                 ushort* __restrict__ yb, int* __restrict__ idx,
                                 float* __restrict__ gate, int* __restrict__ ameta) {
    int row = blockIdx.x;
    const float* xr = x + (size_t)row * D;
    float v[4];
    float s = 0.f, s2 = 0.f;
#pragma unroll
    for (int i = 0; i < 4; i++) {
        v[i] = xr[threadIdx.x + i * 256];
        s += v[i]; s2 += v[i] * v[i];
    }
#pragma unroll
    for (int off = 32; off; off >>= 1) { s += __shfl_down(s, off); s2 += __shfl_down(s2, off); }
    __shared__ float red0[4], red1[4];
    __shared__ float xrow[D];
    int wave = threadIdx.x >> 6, lane = threadIdx.x & 63;
    if (lane == 0) { red0[wave] = s; red1[wave] = s2; }
    __syncthreads();
    float ts = red0[0] + red0[1] + red0[2] + red0[3];
    float ts2 = red1[0] + red1[1] + red1[2] + red1[3];
    float mu = ts * (1.f / D);
    float var = ts2 * (1.f / D) - mu * mu;
    float inv = rsqrtf(var + LN_EPS);
#pragma unroll
    for (int i = 0; i < 4; i++) {
        int d = threadIdx.x + i * 256;
        float o = (v[i] - mu) * inv * w[d] + b[d];
        yb[(size_t)row * D + d] = f2b(o);
        xrow[d] = o;
    }
    __syncthreads();
    if (threadIdx.x < 64) {
        float acc[E];
#pragma unroll
        for (int e = 0; e < E; e++) acc[e] = 0.f;
        for (int d = lane; d < D; d += 64) {
            float xv = xrow[d];
#pragma unroll
            for (int e = 0; e < E; e++) acc[e] += xv * gw[d * E + e];
        }
#pragma unroll
        for (int e = 0; e < E; e++) {
#pragma unroll
            for (int off = 32; off; off >>= 1) acc[e] += __shfl_down(acc[e], off);
        }
        if (lane == 0) {
            float v0 = -1e30f, v1 = -1e30f;
            int i0 = 0, i1 = 0;
#pragma unroll
            for (int e = 0; e < E; e++) {
                float a = acc[e];
                if (a > v0) { v1 = v0; i1 = i0; v0 = a; i0 = e; }
                else if (a > v1) { v1 = a; i1 = e; }
            }
            float g0 = 1.f / (1.f + expf(v1 - v0));
            idx[row * 2] = i0; idx[row * 2 + 1] = i1;
            gate[row * 2] = g0; gate[row * 2 + 1] = 1.f - g0;
            int bb = row >> 10;                              // fused abin_count
            atomicAdd(&ameta[i0 * 4 + bb], 1);
            atomicAdd(&ameta[i1 * 4 + bb], 1);
        }
    }
}

// ---- attn combine + LN + router + fused ffn-bin count.
template <int E>
__global__ void attn_ln_router(const float* __restrict__ src, const float* __restrict__ ob,
                               const int* __restrict__ aidx, const float* __restrict__ aga,
                               const int* __restrict__ ainv, const ushort* __restrict__ Ofb,
                               const float* __restrict__ w, const float* __restrict__ b,
                               const float* __restrict__ gw,
                               float* __restrict__ x1, ushort* __restrict__ yb,
                               int* __restrict__ idx, float* __restrict__ gate,
                               int* __restrict__ fmeta) {
    int row = blockIdx.x;
    int e0 = aidx[row * 2], e1 = aidx[row * 2 + 1];
    float g0a = aga[row * 2], g1a = aga[row * 2 + 1];
    int p0 = ainv[row * 2], p1 = ainv[row * 2 + 1];
    float v[4];
    float s = 0.f, s2 = 0.f;
#pragma unroll
    for (int i = 0; i < 4; i++) {
        int d = threadIdx.x + i * 256;
        float val = src[(size_t)row * D + d]
                  + g0a * ob[e0 * D + d] + g1a * ob[e1 * D + d]
                  + b2f(Ofb[(size_t)p0 * D + d]) + b2f(Ofb[(size_t)p1 * D + d]);
        x1[(size_t)row * D + d] = val;
        v[i] = val; s += val; s2 += val * val;
    }
#pragma unroll
    for (int off = 32; off; off >>= 1) { s += __shfl_down(s, off); s2 += __shfl_down(s2, off); }
    __shared__ float red0[4], red1[4];
    __shared__ float xrow[D];
    int wave = threadIdx.x >> 6, lane = threadIdx.x & 63;
    if (lane == 0) { red0[wave] = s; red1[wave] = s2; }
    __syncthreads();
    float ts = red0[0] + red0[1] + red0[2] + red0[3];
    float ts2 = red1[0] + red1[1] + red1[2] + red1[3];
    float mu = ts * (1.f / D);
    float var = ts2 * (1.f / D) - mu * mu;
    float inv = rsqrtf(var + LN_EPS);
#pragma unroll
    for (int i = 0; i < 4; i++) {
        int d = threadIdx.x + i * 256;
        float o = (v[i] - mu) * inv * w[d] + b[d];
        yb[(size_t)row * D + d] = f2b(o);
        xrow[d] = o;
    }
    __syncthreads();
    if (threadIdx.x < 64) {
        float acc[E];
#pragma unroll
        for (int e = 0; e < E; e++) acc[e] = 0.f;
        for (int d = lane; d < D; d += 64) {
            float xv = xrow[d];
#pragma unroll
            for (int e = 0; e < E; e++) acc[e] += xv * gw[d * E + e];
        }
#pragma unroll
        for (int e = 0; e < E; e++) {
#pragma unroll
            for (int off = 32; off; off >>= 1) acc[e] += __shfl_down(acc[e], off);
        }
        if (lane == 0) {
            float v0 = -1e30f, v1 = -1e30f;
            int i0 = 0, i1 = 0;
#pragma unroll
            for (int e = 0; e < E; e++) {
                float a = acc[e];
                if (a > v0) { v1 = v0; i1 = i0; v0 = a; i0 = e; }
                else if (a > v1) { v1 = a; i1 = e; }
            }
            float g0 = 1.f / (1.f + expf(v1 - v0));
            idx[row * 2] = i0; idx[row * 2 + 1] = i1;
            gate[row * 2] = g0; gate[row * 2 + 1] = 1.f - g0;
            atomicAdd(&fmeta[i0], 1);                        // fused bin_count
            atomicAdd(&fmeta[i1], 1);
        }
    }
}

// ---------------- Attention binning (scan + scatter) ----------------
__global__ void abin_scan(int* __restrict__ meta) {
    if (threadIdx.x == 0 && blockIdx.x == 0) {
        int s = 0;
        for (int bin = 0; bin < 32; bin++) {
            if ((bin & 3) == 0) meta[96 + (bin >> 2)] = s;
            meta[32 + bin] = s; meta[64 + bin] = s; s += meta[bin];
        }
        meta[96 + 8] = s;
    }
}
__global__ void abin_scatter(const int* __restrict__ aidx, int* __restrict__ meta,
                             int* __restrict__ list, int* __restrict__ inv) {
    int i = blockIdx.x * 256 + threadIdx.x;
    if (i < NPAIR) {
        int e = aidx[i];
        int b = (i >> 1) >> 10;
        int pos = atomicAdd(&meta[64 + e * 4 + b], 1);
        list[pos] = i;
        inv[i] = pos;
    }
}

// ---------------- FFN binning (scan + scatter) ----------------
__global__ void bin_scan(int* __restrict__ meta) {
    if (threadIdx.x == 0 && blockIdx.x == 0) {
        int s = 0;
        for (int e = 0; e < EF; e++) { meta[16 + e] = s; meta[32 + e] = s; s += meta[e]; }
    }
}
__global__ void bin_scatter(const int* __restrict__ fidx, int* __restrict__ meta,
                            int* __restrict__ list, int* __restrict__ inv) {
    int i = blockIdx.x * 256 + threadIdx.x;
    if (i < NPAIR) {
        int e = fidx[i];
        int pos = atomicAdd(&meta[32 + e], 1);
        list[pos] = i;
        inv[i] = pos;
    }
}

// ---------------- transpose-convert [R][C] fp32 -> [C][R] bf16 (explicit tile origin) --
template <int R, int C>
__device__ __forceinline__ void convT_body2(const float* __restrict__ src, ushort* __restrict__ dst,
                                            int r0, int c0) {
    __shared__ float tile[32][33];
    int tx = threadIdx.x & 31, ty = threadIdx.x >> 5;  // 256 thr
#pragma unroll
    for (int i = 0; i < 32; i += 8)
        tile[ty + i][tx] = src[(size_t)(r0 + ty + i) * C + c0 + tx];
    __syncthreads();
#pragma unroll
    for (int i = 0; i < 32; i += 8)
        dst[(size_t)(c0 + ty + i) * R + r0 + tx] = f2b(tile[tx][ty + i]);
}
template <int R, int C>
__global__ void convT_kernel(const float* __restrict__ in, ushort* __restrict__ out) {
    int e = blockIdx.z;
    convT_body2<R, C>(in + (size_t)e * R * C, out + (size_t)e * C * R,
                      blockIdx.x * 32, blockIdx.y * 32);
}
// z==0: kw transpose; z==1: vw; z==2: rel conversion; z==3: zero both metas
__global__ void convT_kv(const float* __restrict__ kw, const float* __restrict__ vw,
                         const float* __restrict__ rel,
                         ushort* __restrict__ kwt, ushort* __restrict__ vwt,
                         ushort* __restrict__ relb,
                         int* __restrict__ ameta, int* __restrict__ fmeta) {
    if (blockIdx.z == 0) convT_body2<1024, 128>(kw, kwt, blockIdx.x * 32, blockIdx.y * 32);
    else if (blockIdx.z == 1) convT_body2<1024, 128>(vw, vwt, blockIdx.x * 32, blockIdx.y * 32);
    else if (blockIdx.z == 2) {
        int i = (blockIdx.x * 4 + blockIdx.y) * 256 + threadIdx.x;
        if (i < RNUM * HD) relb[i] = f2b(rel[i]);
    } else {
        if (blockIdx.x == 0 && blockIdx.y == 0) {
            if (threadIdx.x < 105) ameta[threadIdx.x] = 0;
            if (threadIdx.x < 48) fmeta[threadIdx.x] = 0;
        }
    }
}
// merged qw (z<EA) + ow (z>=EA) transposes; flattened 128-block x extent
__global__ void convT_qo(const float* __restrict__ qw, const float* __restrict__ ow,
                         ushort* __restrict__ qwt, ushort* __restrict__ owt) {
    int z = blockIdx.z, bx = blockIdx.x;
    if (z < EA) {
        int r0 = (bx & 31) * 32, c0 = (bx >> 5) * 32;      // 32x4 tiles of [1024][128]
        convT_body2<1024, 128>(qw + (size_t)z * 1024 * 128, qwt + (size_t)z * 128 * 1024, r0, c0);
    } else {
        int e = z - EA;
        int r0 = (bx & 3) * 32, c0 = (bx >> 2) * 32;       // 4x32 tiles of [128][1024]
        convT_body2<128, 1024>(ow + (size_t)e * 128 * 1024, owt + (size_t)e * 1024 * 128, r0, c0);
    }
}
// merged w1 (z<EF) + w2 (z>=EF) transposes; 32x16 grid covers both tilings
__global__ void convT_w(const float* __restrict__ w1, const float* __restrict__ w2,
                        ushort* __restrict__ w1t, ushort* __restrict__ w2t) {
    int z = blockIdx.z;
    if (z < EF) {
        convT_body2<1024, 512>(w1 + (size_t)z * 1024 * 512, w1t + (size_t)z * 512 * 1024,
                               blockIdx.x * 32, blockIdx.y * 32);
    } else {
        int e = z - EF;
        convT_body2<512, 1024>(w2 + (size_t)e * 512 * 1024, w2t + (size_t)e * 1024 * 512,
                               blockIdx.y * 32, blockIdx.x * 32);
    }
}

// ---- qkv: merged kv (z<2) + q (z>=2, expert z-2) split-K MFMA, one dispatch ----------
__global__ __launch_bounds__(256) void qkv_mfma(
    const ushort* __restrict__ xnb, const ushort* __restrict__ kwt,
    const ushort* __restrict__ vwt, const ushort* __restrict__ qwt,
    const int* __restrict__ meta, const int* __restrict__ list,
    float* __restrict__ kpart, float* __restrict__ vpart, float* __restrict__ qpart) {
    int z = blockIdx.z;
    int m0 = blockIdx.x * 64;
    int s = blockIdx.y;
    int kbase = s * 512;
    __shared__ __align__(16) short As[2][64 * BSTR];
    __shared__ __align__(16) short Bs[2][128 * BSTR];
    int tid = threadIdx.x, w = tid >> 6, lane = tid & 63;
    int sr = lane >> 2, sc = (lane & 3) * 8;
    int wr = (w >> 1) * 32, wc = (w & 1) * 64;
    int m16 = lane & 15, q = lane >> 4;
    if (z < 2) {
        const ushort* W = z ? vwt : kwt;
        float* outp = z ? vpart : kpart;
        const ushort* ap = xnb + (size_t)(m0 + w * 16 + sr) * D + kbase + sc;
        const ushort* bp0 = W + (size_t)(w * 32 + sr) * D + kbase + sc;
        const ushort* bp1 = bp0 + (size_t)16 * D;
        f32x4 acc[2][4] = {};
        KLOOP(16, ap, bp0, bp1, 32)
#pragma unroll
        for (int i = 0; i < 2; i++)
#pragma unroll
            for (int r = 0; r < 4; r++) {
                int m = m0 + wr + i * 16 + q * 4 + r;
#pragma unroll
                for (int j = 0; j < 4; j++)
                    outp[((size_t)s * NTOK + m) * HD + wc + j * 16 + m16] = acc[i][j][r];
            }
    } else {
        int e = z - 2;
        int o = meta[96 + e], c = meta[97 + e] - o;
        if (m0 >= c) return;
        int ri = o + m0 + w * 16 + sr; if (ri > NPAIR - 1) ri = NPAIR - 1;
        const ushort* ap = xnb + (size_t)(list[ri] >> 1) * D + kbase + sc;
        const ushort* bp0 = qwt + (size_t)e * HD * D + (size_t)(w * 32 + sr) * D + kbase + sc;
        const ushort* bp1 = bp0 + (size_t)16 * D;
        f32x4 acc[2][4] = {};
        KLOOP(16, ap, bp0, bp1, 32)
#pragma unroll
        for (int i = 0; i < 2; i++)
#pragma unroll
            for (int r = 0; r < 4; r++) {
                int pos = o + m0 + wr + i * 16 + q * 4 + r;
                if (pos < o + c) {
#pragma unroll
                    for (int j = 0; j < 4; j++)
                        qpart[((size_t)s * NPAD + pos) * HD + wc + j * 16 + m16] = acc[i][j][r];
                }
            }
    }
}

// ---- merged reduce: blocks [0,NTOK) = kv path; [NTOK, NTOK+NPAIR) = q path ----------
__global__ void qkv_reduce(const float* __restrict__ kpart, const float* __restrict__ vpart,
                           const float* __restrict__ kb, const float* __restrict__ vb,
                           ushort* __restrict__ kb16, float* __restrict__ vbf,
                           const float* __restrict__ qpart, const float* __restrict__ qb,
                           const int* __restrict__ aidx, const int* __restrict__ list,
                           ushort* __restrict__ Qg) {
    int h = threadIdx.x;  // 128
    if (blockIdx.x < NTOK) {
        int t = blockIdx.x;
        float ka = kb[h], va = vb[h];
#pragma unroll
        for (int s = 0; s < NSPL; s++) {
            ka += kpart[((size_t)s * NTOK + t) * HD + h];
            va += vpart[((size_t)s * NTOK + t) * HD + h];
        }
        kb16[(size_t)t * HD + h] = f2b(ka);
        vbf[(size_t)t * HD + h] = va;
    } else {
        int pos = blockIdx.x - NTOK;
        int e = aidx[list[pos]];
        float a = qb[e * HD + h];
#pragma unroll
        for (int s = 0; s < NSPL; s++) a += qpart[((size_t)s * NPAD + pos) * HD + h];
        Qg[(size_t)pos * HD + h] = f2b(a * QSCALE);
    }
}

// ---------------- rel: MFMA GEMM  R[pos][r] = Qg[pos] . rel[r] ----------------
__global__ __launch_bounds__(256) void rel_mfma(
    const ushort* __restrict__ Qg, const ushort* __restrict__ relb,
    float* __restrict__ R) {
    int m0 = blockIdx.x * 64;
    int n0 = blockIdx.y * 128;
    __shared__ __align__(16) short As[2][64 * BSTR];
    __shared__ __align__(16) short Bs[2][128 * BSTR];
    int tid = threadIdx.x, w = tid >> 6, lane = tid & 63;
    int sr = lane >> 2, sc = (lane & 3) * 8;
    const ushort* ap = Qg + (size_t)(m0 + w * 16 + sr) * HD + sc;
    int r0 = n0 + w * 32 + sr;      if (r0 > RNUM - 1) r0 = RNUM - 1;
    int r1 = n0 + w * 32 + 16 + sr; if (r1 > RNUM - 1) r1 = RNUM - 1;
    const ushort* bp0 = relb + (size_t)r0 * HD + sc;
    const ushort* bp1 = relb + (size_t)r1 * HD + sc;
    int wr = (w >> 1) * 32, wc = (w & 1) * 64;
    int m16 = lane & 15, q = lane >> 4;
    f32x4 acc[2][4] = {};
    KLOOP(4, ap, bp0, bp1, 32)
#pragma unroll
    for (int i = 0; i < 2; i++)
#pragma unroll
        for (int r = 0; r < 4; r++) {
            int pos = m0 + wr + i * 16 + q * 4 + r;
#pragma unroll
            for (int j = 0; j < 4; j++) {
                int n = n0 + wc + j * 16 + m16;
                if (n < RNUM) R[(size_t)pos * RSTRIDE + n] = acc[i][j][r];
            }
        }
}

// ---------------- flash attention, KV-split: each block does 2 of 8 K/V tiles ---------
__global__ __launch_bounds__(256) void flash_attn(
    const ushort* __restrict__ Qg, const ushort* __restrict__ kb16,
    const ushort* __restrict__ vt16, const float* __restrict__ Rbuf,
    const int* __restrict__ meta, const int* __restrict__ list,
    float* __restrict__ Opart, float* __restrict__ mbuf, float* __restrict__ lbuf) {
    int bin = blockIdx.z;
    int o = meta[32 + bin], c = meta[bin];
    int m0 = blockIdx.x * 64;
    if (m0 >= c) return;
    int b = bin & 3;
    int half = blockIdx.y;              // 0..NKV-1
    int TK0 = half * (8 / NKV);         // first K-tile index of this split
    __shared__ __align__(16) ushort QP[64 * 128];       // Q tile, then P tile (wave-private rows)
    __shared__ __align__(16) ushort KV[2][128 * 128];   // [0]=K tile, [1]=V^T tile
    int tid = threadIdx.x, w = tid >> 6, lane = tid & 63;
    int m16 = lane & 15, q = lane >> 4;
    int srow4 = lane >> 4, scol = lane & 15;            // staging: 4 rows x 256B per 1KB issue

#pragma unroll
    for (int t = 0; t < 4; t++) {
        int row = w * 16 + t * 4 + srow4;
        int rg = o + m0 + row; if (rg > NPAIR - 1) rg = NPAIR - 1;   // poison guard
        gll(Qg + (size_t)rg * HD + ((scol ^ (row & 7)) * 8), &QP[(w * 16 + t * 4) * 128]);
    }
#pragma unroll
    for (int u = 0; u < 8; u++) {
        int row = w * 32 + u * 4 + srow4;
        gll(kb16 + ((size_t)b * SEQ + TK0 * 128 + row) * HD + ((scol ^ (row & 7)) * 8),
            &KV[0][(w * 32 + u * 4) * 128]);
    }
#pragma unroll
    for (int u = 0; u < 8; u++) {
        int row = w * 32 + u * 4 + srow4;
        gll(vt16 + ((size_t)b * HD + row) * SEQ + TK0 * 128 + ((scol ^ (row & 7)) * 8),
            &KV[1][(w * 32 + u * 4) * 128]);
    }

    int qpos[4]; const float* Rrow[4];
#pragma unroll
    for (int r = 0; r < 4; r++) {
        int pos = o + m0 + w * 16 + q * 4 + r;
        int pc = pos < NPAIR ? pos : NPAIR - 1;
        qpos[r] = (list[pc] >> 1) & (SEQ - 1);
        Rrow[r] = Rbuf + (size_t)pc * RSTRIDE;
    }
    float m_run[4], l_run[4];
#pragma unroll
    for (int r = 0; r < 4; r++) { m_run[r] = -1e30f; l_run[r] = 0.f; }
    f32x4 acc_o[8];
#pragma unroll
    for (int j = 0; j < 8; j++) acc_o[j] = (f32x4){0.f, 0.f, 0.f, 0.f};

    wait_vm16();   // own-wave Q staged (Q rows are wave-private; no barrier needed)
    bf16x8 qf[4];
#pragma unroll
    for (int kk = 0; kk < 4; kk++)
        qf[kk] = *(const bf16x8*)&QP[(w * 16 + m16) * 128 + (((q + 4 * kk) ^ (m16 & 7)) * 8)];

#pragma unroll
    for (int t2 = 0; t2 < 8 / NKV; t2++) {
        int kt = TK0 + t2;
        wait_vm8();          // own-wave K_kt done (V_kt may be in flight)
        bar();               // all waves' K tile present
        f32x4 s_[8];
#pragma unroll
        for (int j = 0; j < 8; j++) s_[j] = (f32x4){0.f, 0.f, 0.f, 0.f};
#pragma unroll
        for (int kk = 0; kk < 4; kk++) {
#pragma unroll
            for (int j = 0; j < 8; j++) {
                bf16x8 bb = *(const bf16x8*)&KV[0][(j * 16 + m16) * 128 + (((q + 4 * kk) ^ (m16 & 7)) * 8)];
                s_[j] = __builtin_amdgcn_mfma_f32_16x16x32_bf16(qf[kk], bb, s_[j], 0, 0, 0);
            }
        }
        float mloc[4] = {-1e30f, -1e30f, -1e30f, -1e30f};
#pragma unroll
        for (int j = 0; j < 8; j++) {
            int key = kt * 128 + j * 16 + m16;
#pragma unroll
            for (int r = 0; r < 4; r++) {
                int rix = key - qpos[r];
                rix = (rix < -MAXPOS ? -MAXPOS : (rix > MAXPOS ? MAXPOS : rix)) + MAXPOS;
                float vv = s_[j][r] + Rrow[r][rix];
                s_[j][r] = vv;
                mloc[r] = fmaxf(mloc[r], vv);
            }
        }
#pragma unroll
        for (int off = 8; off; off >>= 1)
#pragma unroll
            for (int r = 0; r < 4; r++) mloc[r] = fmaxf(mloc[r], __shfl_xor(mloc[r], off, 16));
        float scale_[4], lloc[4] = {0.f, 0.f, 0.f, 0.f};
#pragma unroll
        for (int r = 0; r < 4; r++) {
            float mn = fmaxf(m_run[r], mloc[r]);
            scale_[r] = __expf(m_run[r] - mn);
            m_run[r] = mn;
        }
#pragma unroll
        for (int j = 0; j < 8; j++) {
#pragma unroll
            for (int r = 0; r < 4; r++) {
                float p = __expf(s_[j][r] - m_run[r]);
                lloc[r] += p;
                int row = q * 4 + r;
                QP[(w * 16 + row) * 128 + ((j * 16 + m16) ^ ((row & 7) * 8))] = f2b(p);
            }
        }
#pragma unroll
        for (int off = 8; off; off >>= 1)
#pragma unroll
            for (int r = 0; r < 4; r++) lloc[r] += __shfl_xor(lloc[r], off, 16);
#pragma unroll
        for (int r = 0; r < 4; r++) l_run[r] = l_run[r] * scale_[r] + lloc[r];
#pragma unroll
        for (int j = 0; j < 8; j++)
#pragma unroll
            for (int r = 0; r < 4; r++) acc_o[j][r] *= scale_[r];
        bar();               // all waves done reading K tile
        if (t2 < 8 / NKV - 1) {
#pragma unroll
            for (int u = 0; u < 8; u++) {
                int row = w * 32 + u * 4 + srow4;
                gll(kb16 + ((size_t)b * SEQ + (kt + 1) * 128 + row) * HD + ((scol ^ (row & 7)) * 8),
                    &KV[0][(w * 32 + u * 4) * 128]);
            }
            wait_vm8();      // own-wave V_kt done (older than K_{kt+1} just issued)
        } else {
            wait_vm0();
        }
        bar();               // all waves' V tile present
#pragma unroll
        for (int kk = 0; kk < 4; kk++) {
            bf16x8 pf = *(const bf16x8*)&QP[(w * 16 + m16) * 128 + (((q + 4 * kk) ^ (m16 & 7)) * 8)];
#pragma unroll
            for (int j = 0; j < 8; j++) {
                bf16x8 vv = *(const bf16x8*)&KV[1][(j * 16 + m16) * 128 + (((q + 4 * kk) ^ (m16 & 7)) * 8)];
                acc_o[j] = __builtin_amdgcn_mfma_f32_16x16x32_bf16(pf, vv, acc_o[j], 0, 0, 0);
            }
        }
        bar();               // all waves done reading V tile
        if (t2 < 8 / NKV - 1) {
#pragma unroll
            for (int u = 0; u < 8; u++) {
                int row = w * 32 + u * 4 + srow4;
                gll(vt16 + ((size_t)b * HD + row) * SEQ + (kt + 1) * 128 + ((scol ^ (row & 7)) * 8),
                    &KV[1][(w * 32 + u * 4) * 128]);
            }
        }
    }
#pragma unroll
    for (int r = 0; r < 4; r++) {
        int pos = o + m0 + w * 16 + q * 4 + r;
        if (pos < o + c) {
            if (m16 == 0) {
                mbuf[(size_t)half * NPAD + pos] = m_run[r];
                lbuf[(size_t)half * NPAD + pos] = l_run[r];
            }
#pragma unroll
            for (int j = 0; j < 8; j++)
                Opart[((size_t)half * NPAD + pos) * HD + j * 16 + m16] = acc_o[j][r];
        }
    }
}

// ---------------- flash combine: merge NKV partials, apply gate, write bf16 ctx -------
__global__ void flash_combine(const float* __restrict__ Opart, const float* __restrict__ mbuf,
                              const float* __restrict__ lbuf, const float* __restrict__ aga,
                              const int* __restrict__ list, ushort* __restrict__ ctx16) {
    int pos = blockIdx.x, h = threadIdx.x;  // 128
    float M = -1e30f;
#pragma unroll
    for (int i = 0; i < NKV; i++) M = fmaxf(M, mbuf[(size_t)i * NPAD + pos]);
    float L = 0.f, O = 0.f;
#pragma unroll
    for (int i = 0; i < NKV; i++) {
        float e = __expf(mbuf[(size_t)i * NPAD + pos] - M);
        L += lbuf[(size_t)i * NPAD + pos] * e;
        O += Opart[((size_t)i * NPAD + pos) * HD + h] * e;
    }
    float g = aga[list[pos]] / L;
    ctx16[(size_t)pos * HD + h] = f2b(O * g);
}

// ---------------- o: MFMA ctx@o_w, dense bf16 per-pair rows ----------------
__global__ __launch_bounds__(256) void o_mfma(
    const ushort* __restrict__ ctx16, const ushort* __restrict__ owt,
    const int* __restrict__ meta, ushort* __restrict__ Ofb) {
    int e = blockIdx.z;
    int o = meta[96 + e], c = meta[97 + e] - o;
    int m0 = blockIdx.x * 64;
    if (m0 >= c) return;
    int n0 = blockIdx.y * 128;
    __shared__ __align__(16) short As[2][64 * BSTR];
    __shared__ __align__(16) short Bs[2][128 * BSTR];
    int tid = threadIdx.x, w = tid >> 6, lane = tid & 63;
    int sr = lane >> 2, sc = (lane & 3) * 8;
    int ar = o + m0 + w * 16 + sr; if (ar > NPAIR - 1) ar = NPAIR - 1;   // poison guard
    const ushort* ap = ctx16 + (size_t)ar * HD + sc;
    const ushort* bp0 = owt + (size_t)e * D * HD + (size_t)(n0 + w * 32 + sr) * HD + sc;
    const ushort* bp1 = bp0 + (size_t)16 * HD;
    int wr = (w >> 1) * 32, wc = (w & 1) * 64;
    int m16 = lane & 15, q = lane >> 4;
    f32x4 acc[2][4] = {};
    KLOOP(4, ap, bp0, bp1, 32)
#pragma unroll
    for (int i = 0; i < 2; i++)
#pragma unroll
        for (int r = 0; r < 4; r++) {
            int pos = o + m0 + wr + i * 16 + q * 4 + r;
            if (pos < o + c) {
#pragma unroll
                for (int j = 0; j < 4; j++)
                    Ofb[(size_t)pos * D + n0 + wc + j * 16 + m16] = f2b(acc[i][j][r]);
            }
        }
}

// ---------------- FFN GEMM1: Hb = g*relu(xn2 @ W1 + b1) ----------------
__global__ __launch_bounds__(256) void ffn_mfma1(
    const ushort* __restrict__ xnb2, const ushort* __restrict__ w1t,
    const float* __restrict__ b1, const int* __restrict__ meta,
    const int* __restrict__ list, const float* __restrict__ fga,
    ushort* __restrict__ Hb) {
    int e = blockIdx.z;
    int o = meta[16 + e], c = meta[e];
    int m0 = blockIdx.x * 64;
    if (m0 >= c) return;
    int n0 = blockIdx.y * 128;
    __shared__ __align__(16) short As[2][64 * BSTR];
    __shared__ __align__(16) short Bs[2][128 * BSTR];
    int tid = threadIdx.x, w = tid >> 6, lane = tid & 63;
    int sr = lane >> 2, sc = (lane & 3) * 8;
    int ri = o + m0 + w * 16 + sr; if (ri > NPAIR - 1) ri = NPAIR - 1;
    const ushort* ap = xnb2 + (size_t)(list[ri] >> 1) * D + sc;
    const ushort* bp0 = w1t + ((size_t)e * FH + n0 + w * 32 + sr) * D + sc;
    const ushort* bp1 = bp0 + (size_t)16 * D;
    int wr = (w >> 1) * 32, wc = (w & 1) * 64;
    int m16 = lane & 15, q = lane >> 4;
    f32x4 acc[2][4] = {};
    KLOOP(32, ap, bp0, bp1, 32)
#pragma unroll
    for (int i = 0; i < 2; i++)
#pragma unroll
        for (int r = 0; r < 4; r++) {
            int pos = o + m0 + wr + i * 16 + q * 4 + r;
            if (pos < o + c) {
                float g = fga[list[pos]];
#pragma unroll
                for (int j = 0; j < 4; j++) {
                    int n = n0 + wc + j * 16 + m16;
                    Hb[(size_t)pos * FH + n] = f2b(g * fmaxf(acc[i][j][r] + b1[e * FH + n], 0.f));
                }
            }
        }
}

// ---------------- FFN GEMM2: Of2b[pos] = Hb @ W2 (dense bf16 rows) ----------------
__global__ __launch_bounds__(256) void ffn_mfma2(
    const ushort* __restrict__ Hb, const ushort* __restrict__ w2t,
    const int* __restrict__ meta, ushort* __restrict__ Of2b) {
    int e = blockIdx.z;
    int o = meta[16 + e], c = meta[e];
    int m0 = blockIdx.x * 64;
    if (m0 >= c) return;
    int n0 = blockIdx.y * 128;
    __shared__ __align__(16) short As[2][64 * BSTR];
    __shared__ __align__(16) short Bs[2][128 * BSTR];
    int tid = threadIdx.x, w = tid >> 6, lane = tid & 63;
    int sr = lane >> 2, sc = (lane & 3) * 8;
    int ar = o + m0 + w * 16 + sr; if (ar > NPAIR - 1) ar = NPAIR - 1;   // poison guard
    const ushort* ap = Hb + (size_t)ar * FH + sc;
    const ushort* bp0 = w2t + ((size_t)e * D + n0 + w * 32 + sr) * FH + sc;
    const ushort* bp1 = bp0 + (size_t)16 * FH;
    int wr = (w >> 1) * 32, wc = (w & 1) * 64;
    int m16 = lane & 15, q = lane >> 4;
    f32x4 acc[2][4] = {};
    KLOOP(16, ap, bp0, bp1, 32)
#pragma unroll
    for (int i = 0; i < 2; i++)
#pragma unroll
        for (int r = 0; r < 4; r++) {
            int pos = o + m0 + wr + i * 16 + q * 4 + r;
            if (pos < o + c) {
#pragma unroll
                for (int j = 0; j < 4; j++)
                    Of2b[(size_t)pos * D + n0 + wc + j * 16 + m16] = f2b(acc[i][j][r]);
            }
        }
}

// ---------------- FFN combine ----------------
__global__ void ffn_combine(const float* __restrict__ x1, const float* __restrict__ b2,
                            const int* __restrict__ fidx, const float* __restrict__ fga,
                            const int* __restrict__ finv, const ushort* __restrict__ Of2b,
                            float* __restrict__ out) {
    int t = blockIdx.x, tid = threadIdx.x;
    int e0 = fidx[t * 2], e1 = fidx[t * 2 + 1];
    float g0 = fga[t * 2], g1 = fga[t * 2 + 1];
    int p0 = finv[t * 2], p1 = finv[t * 2 + 1];
#pragma unroll
    for (int i = 0; i < 4; i++) {
        int d = tid + i * 256;
        out[(size_t)t * D + d] = x1[(size_t)t * D + d]
                               + g0 * b2[e0 * D + d] + g1 * b2[e1 * D + d]
                               + b2f(Of2b[(size_t)p0 * D + d]) + b2f(Of2b[(size_t)p1 * D + d]);
    }
}

extern "C" void kernel_launch(void* const* d_in, const int* in_sizes, int n_in,
                              void* d_out, int out_size, void* d_ws, size_t ws_size,
                              hipStream_t stream) {
    const float* src   = (const float*)d_in[0];
    const float* ln1_w = (const float*)d_in[1];
    const float* ln1_b = (const float*)d_in[2];
    const float* ln2_w = (const float*)d_in[3];
    const float* ln2_b = (const float*)d_in[4];
    const float* agw   = (const float*)d_in[5];
    const float* qw    = (const float*)d_in[6];
    const float* qb    = (const float*)d_in[7];
    const float* kw    = (const float*)d_in[8];
    const float* kb    = (const float*)d_in[9];
    const float* vw    = (const float*)d_in[10];
    const float* vb    = (const float*)d_in[11];
    const float* ow    = (const float*)d_in[12];
    const float* ob    = (const float*)d_in[13];
    const float* rel   = (const float*)d_in[14];
    const float* fgw   = (const float*)d_in[15];
    const float* w1    = (const float*)d_in[16];
    const float* b1    = (const float*)d_in[17];
    const float* w2    = (const float*)d_in[18];
    const float* b2    = (const float*)d_in[19];
    float* out = (float*)d_out;

    char* p = (char*)d_ws;
    float* xn1  = (float*)p; p += (size_t)NTOK * D * 4;               // (unused slot, layout stability)
    float* x1   = (float*)p; p += (size_t)NTOK * D * 4;
    char*  sreg = p;         p += (size_t)NPAD * SEQ * 4;             // 34.1 MB
    ushort* Ofb  = (ushort*)sreg;                                     // attn: o rows (17 MB)
    ushort* w1t  = (ushort*)sreg;                                     // FFN: 16.78 MB
    ushort* w2t  = (ushort*)(sreg + (size_t)16777216);                // FFN: 16.78 MB
    char*  reg  = p;         p += (size_t)NPAD * 128 * 6 + (size_t)NPAIR * RSTRIDE * 4;
    ushort* ctx16 = (ushort*)reg;                                     // bf16 ctx (2.13 MB slot)
    ushort* Qg   = (ushort*)(reg + (size_t)NPAD * 128 * 4);           // 2.13 MB
    float*  Rbuf = (float*)(reg + (size_t)NPAD * 128 * 6);            // 4.33 MB
    ushort* Hb   = (ushort*)reg;                                      // FFN hidden (8.52 MB)
    char*  arena = p;        p += (size_t)4 * NPAD * 128 * 4;         // 17.04 MB
    float*  kpart = (float*)arena;
    float*  vpart = (float*)(arena + (size_t)NSPL * NTOK * HD * 4);
    float*  qpart = (float*)(arena + (size_t)2 * NSPL * NTOK * HD * 4);
    float*  Opart = (float*)arena;                                    // flash partials (NKV*NPAD*HD f32)
    ushort* Of2b  = (ushort*)arena;
    ushort* kb16 = (ushort*)p; p += (size_t)NTOK * HD * 2;
    float* vbf  = (float*)p; p += (size_t)NTOK * HD * 4;
    ushort* vt16 = (ushort*)p; p += (size_t)NTOK * HD * 2;
    ushort* kwt = (ushort*)p; p += (size_t)HD * D * 2;
    ushort* vwt = (ushort*)p; p += (size_t)HD * D * 2;
    ushort* qwt = (ushort*)p; p += (size_t)EA * HD * D * 2;
    ushort* owt = (ushort*)p; p += (size_t)EA * D * HD * 2;
    ushort* relb = (ushort*)p; p += (size_t)RNUM * HD * 2 + 256;
    int*   aidx = (int*)p;   p += NPAIR * 4;
    float* aga  = (float*)p; p += NPAIR * 4;
    int*   fidx = (int*)p;   p += NPAIR * 4;
    float* fga  = (float*)p; p += NPAIR * 4;
    int*   ameta = (int*)p;  p += 128 * 4;
    int*   alist = (int*)p;  p += NPAIR * 4;
    int*   ainv = (int*)p;   p += NPAIR * 4;
    int*   fmeta = (int*)p;  p += 64 * 4;
    int*   flist = (int*)p;  p += NPAIR * 4;
    int*   finv = (int*)p;   p += NPAIR * 4;
    ushort* xnb = (ushort*)p; p += (size_t)NTOK * D * 2;              // bf16 LN out (GEMM A operand)
    float* mbuf = (float*)p; p += (size_t)NKV * NPAD * 4;             // flash row-max stats
    float* lbuf = (float*)p; p += (size_t)NKV * NPAD * 4;             // flash row-sum stats
    (void)xn1;

    // ---- attention ----
    convT_kv<<<dim3(32, 4, 4), 256, 0, stream>>>(kw, vw, rel, kwt, vwt, relb, ameta, fmeta);
    ln_router_kernel<EA><<<NTOK, 256, 0, stream>>>(src, ln1_w, ln1_b, agw, xnb, aidx, aga, ameta);
    abin_scan<<<1, 64, 0, stream>>>(ameta);
    abin_scatter<<<NPAIR / 256, 256, 0, stream>>>(aidx, ameta, alist, ainv);
    convT_qo<<<dim3(128, 1, 2 * EA), 256, 0, stream>>>(qw, ow, qwt, owt);
    qkv_mfma<<<dim3(64, NSPL, 2 + EA), 256, 0, stream>>>(xnb, kwt, vwt, qwt, ameta, alist,
                                                          kpart, vpart, qpart);
    qkv_reduce<<<NTOK + NPAIR, 128, 0, stream>>>(kpart, vpart, kb, vb, kb16, vbf,
                                                 qpart, qb, aidx, alist, Qg);
    convT_kernel<1024, 128><<<dim3(32, 4, 4), 256, 0, stream>>>(vbf, vt16);
    rel_mfma<<<dim3(NPAIR / 64, 2), 256, 0, stream>>>(Qg, relb, Rbuf);
    flash_attn<<<dim3(12, NKV, 32), 256, 0, stream>>>(Qg, kb16, vt16, Rbuf, ameta, alist,
                                                      Opart, mbuf, lbuf);
    flash_combine<<<NPAIR, 128, 0, stream>>>(Opart, mbuf, lbuf, aga, alist, ctx16);
    o_mfma<<<dim3(40, 8, EA), 256, 0, stream>>>(ctx16, owt, ameta, Ofb);
    attn_ln_router<EF><<<NTOK, 256, 0, stream>>>(src, ob, aidx, aga, ainv, Ofb,
                                                 ln2_w, ln2_b, fgw, x1, xnb, fidx, fga, fmeta);

    // ---- FFN ----
    bin_scan<<<1, 64, 0, stream>>>(fmeta);
    bin_scatter<<<NPAIR / 256, 256, 0, stream>>>(fidx, fmeta, flist, finv);
    convT_w<<<dim3(32, 16, 2 * EF), 256, 0, stream>>>(w1, w2, w1t, w2t);
    ffn_mfma1<<<dim3(20, 4, EF), 256, 0, stream>>>(xnb, w1t, b1, fmeta, flist, fga, Hb);
    ffn_mfma2<<<dim3(20, 8, EF), 256, 0, stream>>>(Hb, w2t, fmeta, Of2b);
    ffn_combine<<<NTOK, 256, 0, stream>>>(x1, b2, fidx, fga, finv, Of2b, out);
}

// Round 16
// 466.097 us; speedup vs baseline: 1.1649x; 1.1649x over previous
//
#include <hip/hip_runtime.h>

#define D 1024
#define HD 128
#define EA 8
#define EF 16
#define FH 512
#define MAXPOS 64
#define RNUM 129
#define RSTRIDE 132
#define SEQ 1024
#define NTOK 4096
#define NPAIR (NTOK * 2)
#define NPAD 8320          // NPAIR + 128 slack
#define LN_EPS 1e-5f
#define QSCALE 0.08838834764831845f
#define BSTR 32            // linear LDS row stride in bf16 elems (global_load_lds needs linear)
#define NSPL 2             // split-K splits (green structure)
#define NKV 4              // flash: KV splits (2 K-tiles each)

typedef __attribute__((ext_vector_type(8))) short bf16x8;
typedef __attribute__((ext_vector_type(4))) float f32x4;
typedef __attribute__((ext_vector_type(8))) unsigned short u16x8;

__device__ inline ushort f2b(float f) {
    union { float f; unsigned u; } v; v.f = f;
    unsigned r = (v.u + 0x7fffu + ((v.u >> 16) & 1u)) >> 16;
    return (ushort)r;
}
__device__ inline float b2f(ushort u) {
    union { unsigned u; float f; } v; v.u = (unsigned)u << 16; return v.f;
}

// async global->LDS, 16B per lane, dest = wave-uniform base + lane*16
__device__ __forceinline__ void gll(const void* g, void* l) {
    __builtin_amdgcn_global_load_lds((const __attribute__((address_space(1))) void*)g,
                                     (__attribute__((address_space(3))) void*)l, 16, 0, 0);
}
__device__ __forceinline__ void wait_vm0()  { asm volatile("s_waitcnt vmcnt(0)" ::: "memory"); }
__device__ __forceinline__ void wait_vm3()  { asm volatile("s_waitcnt vmcnt(3)" ::: "memory"); }
__device__ __forceinline__ void wait_vm8()  { asm volatile("s_waitcnt vmcnt(8)" ::: "memory"); }
__device__ __forceinline__ void wait_vm16() { asm volatile("s_waitcnt vmcnt(16)" ::: "memory"); }
__device__ __forceinline__ void bar() { __builtin_amdgcn_s_barrier(); }

// one double-buffer compute step: 64x128 tile, wave = 32x64
__device__ inline void mfma_step(const short* Asb, const short* Bsb,
                                 int wr, int wc, int m16, int q, f32x4 (&acc)[2][4]) {
    bf16x8 af[2], bfr[4];
#pragma unroll
    for (int i = 0; i < 2; i++) af[i] = *(const bf16x8*)&Asb[(wr + i * 16 + m16) * BSTR + q * 8];
#pragma unroll
    for (int j = 0; j < 4; j++) bfr[j] = *(const bf16x8*)&Bsb[(wc + j * 16 + m16) * BSTR + q * 8];
#pragma unroll
    for (int i = 0; i < 2; i++)
#pragma unroll
        for (int j = 0; j < 4; j++)
            acc[i][j] = __builtin_amdgcn_mfma_f32_16x16x32_bf16(af[i], bfr[j], acc[i][j], 0, 0, 0);
}

// depth-2 counted-vmcnt K-loop (T3/T4-lite).
#define KLOOP(NK, AP, BP0, BP1, STRIDE)                                          \
    gll(AP, &As[0][w * 512]); gll(BP0, &Bs[0][w * 1024]); gll(BP1, &Bs[0][w * 1024 + 512]); \
    gll(AP + STRIDE, &As[1][w * 512]); gll(BP0 + STRIDE, &Bs[1][w * 1024]);      \
    gll(BP1 + STRIDE, &Bs[1][w * 1024 + 512]);                                   \
    {                                                                            \
        int cur = 0;                                                             \
        for (int k = 0; k < NK; k++) {                                           \
            if (k < NK - 1) wait_vm3(); else wait_vm0();                         \
            bar();                                                               \
            mfma_step(As[cur], Bs[cur], wr, wc, m16, q, acc);                    \
            if (k + 2 < NK) {                                                    \
                bar();                                                           \
                gll(AP + (k + 2) * STRIDE, &As[cur][w * 512]);                   \
                gll(BP0 + (k + 2) * STRIDE, &Bs[cur][w * 1024]);                 \
                gll(BP1 + (k + 2) * STRIDE, &Bs[cur][w * 1024 + 512]);           \
            }                                                                    \
            cur ^= 1;                                                            \
        }                                                                        \
    }

// ---- LayerNorm + fused router (bit-exact r2-lineage router; fp32 row staged in LDS,
//      wave 0 replays the identical (d=lane; d+=64) loop, shfl tree, and top-2 code).
template <int E>
__global__ void ln_router_kernel(const float* __restrict__ x, const float* __restrict__ w,
                                 const float* __restrict__ b, const float* __restrict__ gw,
                                 ushort* __restrict__ yb, int* __restrict__ idx,
                                 float* __restrict__ gate) {
    int row = blockIdx.x;
    const float* xr = x + (size_t)row * D;
    float v[4];
    float s = 0.f, s2 = 0.f;
#pragma unroll
    for (int i = 0; i < 4; i++) {
        v[i] = xr[threadIdx.x + i * 256];
        s += v[i]; s2 += v[i] * v[i];
    }
#pragma unroll
    for (int off = 32; off; off >>= 1) { s += __shfl_down(s, off); s2 += __shfl_down(s2, off); }
    __shared__ float red0[4], red1[4];
    __shared__ float xrow[D];
    int wave = threadIdx.x >> 6, lane = threadIdx.x & 63;
    if (lane == 0) { red0[wave] = s; red1[wave] = s2; }
    __syncthreads();
    float ts = red0[0] + red0[1] + red0[2] + red0[3];
    float ts2 = red1[0] + red1[1] + red1[2] + red1[3];
    float mu = ts * (1.f / D);
    float var = ts2 * (1.f / D) - mu * mu;
    float inv = rsqrtf(var + LN_EPS);
#pragma unroll
    for (int i = 0; i < 4; i++) {
        int d = threadIdx.x + i * 256;
        float o = (v[i] - mu) * inv * w[d] + b[d];
        yb[(size_t)row * D + d] = f2b(o);
        xrow[d] = o;
    }
    __syncthreads();
    if (threadIdx.x < 64) {
        float acc[E];
#pragma unroll
        for (int e = 0; e < E; e++) acc[e] = 0.f;
        for (int d = lane; d < D; d += 64) {
            float xv = xrow[d];
#pragma unroll
            for (int e = 0; e < E; e++) acc[e] += xv * gw[d * E + e];
        }
#pragma unroll
        for (int e = 0; e < E; e++) {
#pragma unroll
            for (int off = 32; off; off >>= 1) acc[e] += __shfl_down(acc[e], off);
        }
        if (lane == 0) {
            float v0 = -1e30f, v1 = -1e30f;
            int i0 = 0, i1 = 0;
#pragma unroll
            for (int e = 0; e < E; e++) {
                float a = acc[e];
                if (a > v0) { v1 = v0; i1 = i0; v0 = a; i0 = e; }
                else if (a > v1) { v1 = a; i1 = e; }
            }
            float g0 = 1.f / (1.f + expf(v1 - v0));
            idx[row * 2] = i0; idx[row * 2 + 1] = i1;
            gate[row * 2] = g0; gate[row * 2 + 1] = 1.f - g0;
        }
    }
}

// ---- attn combine + LN + router, fused (x1 computed in registers, written, then the
//      bit-exact ln_router body runs on the same values).
template <int E>
__global__ void attn_ln_router(const float* __restrict__ src, const float* __restrict__ ob,
                               const int* __restrict__ aidx, const float* __restrict__ aga,
                               const int* __restrict__ ainv, const ushort* __restrict__ Ofb,
                               const float* __restrict__ w, const float* __restrict__ b,
                               const float* __restrict__ gw,
                               float* __restrict__ x1, ushort* __restrict__ yb,
                               int* __restrict__ idx, float* __restrict__ gate) {
    int row = blockIdx.x;
    int e0 = aidx[row * 2], e1 = aidx[row * 2 + 1];
    float g0a = aga[row * 2], g1a = aga[row * 2 + 1];
    int p0 = ainv[row * 2], p1 = ainv[row * 2 + 1];
    float v[4];
    float s = 0.f, s2 = 0.f;
#pragma unroll
    for (int i = 0; i < 4; i++) {
        int d = threadIdx.x + i * 256;
        float val = src[(size_t)row * D + d]
                  + g0a * ob[e0 * D + d] + g1a * ob[e1 * D + d]
                  + b2f(Ofb[(size_t)p0 * D + d]) + b2f(Ofb[(size_t)p1 * D + d]);
        x1[(size_t)row * D + d] = val;
        v[i] = val; s += val; s2 += val * val;
    }
#pragma unroll
    for (int off = 32; off; off >>= 1) { s += __shfl_down(s, off); s2 += __shfl_down(s2, off); }
    __shared__ float red0[4], red1[4];
    __shared__ float xrow[D];
    int wave = threadIdx.x >> 6, lane = threadIdx.x & 63;
    if (lane == 0) { red0[wave] = s; red1[wave] = s2; }
    __syncthreads();
    float ts = red0[0] + red0[1] + red0[2] + red0[3];
    float ts2 = red1[0] + red1[1] + red1[2] + red1[3];
    float mu = ts * (1.f / D);
    float var = ts2 * (1.f / D) - mu * mu;
    float inv = rsqrtf(var + LN_EPS);
#pragma unroll
    for (int i = 0; i < 4; i++) {
        int d = threadIdx.x + i * 256;
        float o = (v[i] - mu) * inv * w[d] + b[d];
        yb[(size_t)row * D + d] = f2b(o);
        xrow[d] = o;
    }
    __syncthreads();
    if (threadIdx.x < 64) {
        float acc[E];
#pragma unroll
        for (int e = 0; e < E; e++) acc[e] = 0.f;
        for (int d = lane; d < D; d += 64) {
            float xv = xrow[d];
#pragma unroll
            for (int e = 0; e < E; e++) acc[e] += xv * gw[d * E + e];
        }
#pragma unroll
        for (int e = 0; e < E; e++) {
#pragma unroll
            for (int off = 32; off; off >>= 1) acc[e] += __shfl_down(acc[e], off);
        }
        if (lane == 0) {
            float v0 = -1e30f, v1 = -1e30f;
            int i0 = 0, i1 = 0;
#pragma unroll
            for (int e = 0; e < E; e++) {
                float a = acc[e];
                if (a > v0) { v1 = v0; i1 = i0; v0 = a; i0 = e; }
                else if (a > v1) { v1 = a; i1 = e; }
            }
            float g0 = 1.f / (1.f + expf(v1 - v0));
            idx[row * 2] = i0; idx[row * 2 + 1] = i1;
            gate[row * 2] = g0; gate[row * 2 + 1] = 1.f - g0;
        }
    }
}

// ---------------- meta zeroing (attn + ffn merged) ----------------
__global__ void zero_meta(int* __restrict__ ameta, int* __restrict__ fmeta) {
    if (threadIdx.x < 105) ameta[threadIdx.x] = 0;
    if (threadIdx.x < 48) fmeta[threadIdx.x] = 0;
}

// ---------------- Attention binning: 32 bins keyed (expert*4 + batch) ----------------
__global__ void abin_count(const int* __restrict__ aidx, int* __restrict__ meta) {
    int i = blockIdx.x * 256 + threadIdx.x;
    if (i < NPAIR) {
        int e = aidx[i];
        int b = (i >> 1) >> 10;
        atomicAdd(&meta[e * 4 + b], 1);
    }
}
__global__ void abin_scan(int* __restrict__ meta) {
    if (threadIdx.x == 0 && blockIdx.x == 0) {
        int s = 0;
        for (int bin = 0; bin < 32; bin++) {
            if ((bin & 3) == 0) meta[96 + (bin >> 2)] = s;
            meta[32 + bin] = s; meta[64 + bin] = s; s += meta[bin];
        }
        meta[96 + 8] = s;
    }
}
__global__ void abin_scatter(const int* __restrict__ aidx, int* __restrict__ meta,
                             int* __restrict__ list, int* __restrict__ inv) {
    int i = blockIdx.x * 256 + threadIdx.x;
    if (i < NPAIR) {
        int e = aidx[i];
        int b = (i >> 1) >> 10;
        int pos = atomicAdd(&meta[64 + e * 4 + b], 1);
        list[pos] = i;
        inv[i] = pos;
    }
}

// ---------------- FFN binning ----------------
__global__ void bin_count(const int* __restrict__ fidx, int* __restrict__ meta) {
    int i = blockIdx.x * 256 + threadIdx.x;
    if (i < NPAIR) atomicAdd(&meta[fidx[i]], 1);
}
__global__ void bin_scan(int* __restrict__ meta) {
    if (threadIdx.x == 0 && blockIdx.x == 0) {
        int s = 0;
        for (int e = 0; e < EF; e++) { meta[16 + e] = s; meta[32 + e] = s; s += meta[e]; }
    }
}
__global__ void bin_scatter(const int* __restrict__ fidx, int* __restrict__ meta,
                            int* __restrict__ list, int* __restrict__ inv) {
    int i = blockIdx.x * 256 + threadIdx.x;
    if (i < NPAIR) {
        int e = fidx[i];
        int pos = atomicAdd(&meta[32 + e], 1);
        list[pos] = i;
        inv[i] = pos;
    }
}

// ---------------- transpose-convert [R][C] fp32 -> [C][R] bf16 (explicit tile origin) --
template <int R, int C>
__device__ __forceinline__ void convT_body2(const float* __restrict__ src, ushort* __restrict__ dst,
                                            int r0, int c0) {
    __shared__ float tile[32][33];
    int tx = threadIdx.x & 31, ty = threadIdx.x >> 5;  // 256 thr
#pragma unroll
    for (int i = 0; i < 32; i += 8)
        tile[ty + i][tx] = src[(size_t)(r0 + ty + i) * C + c0 + tx];
    __syncthreads();
#pragma unroll
    for (int i = 0; i < 32; i += 8)
        dst[(size_t)(c0 + ty + i) * R + r0 + tx] = f2b(tile[tx][ty + i]);
}
template <int R, int C>
__global__ void convT_kernel(const float* __restrict__ in, ushort* __restrict__ out) {
    int e = blockIdx.z;
    convT_body2<R, C>(in + (size_t)e * R * C, out + (size_t)e * C * R,
                      blockIdx.x * 32, blockIdx.y * 32);
}
// z==0: kw transpose; z==1: vw transpose; z==2: rel elementwise conversion
__global__ void convT_kv(const float* __restrict__ kw, const float* __restrict__ vw,
                         const float* __restrict__ rel,
                         ushort* __restrict__ kwt, ushort* __restrict__ vwt,
                         ushort* __restrict__ relb) {
    if (blockIdx.z == 0) convT_body2<1024, 128>(kw, kwt, blockIdx.x * 32, blockIdx.y * 32);
    else if (blockIdx.z == 1) convT_body2<1024, 128>(vw, vwt, blockIdx.x * 32, blockIdx.y * 32);
    else {
        int i = (blockIdx.x * 4 + blockIdx.y) * 256 + threadIdx.x;
        if (i < RNUM * HD) relb[i] = f2b(rel[i]);
    }
}
// merged qw (z<EA) + ow (z>=EA) transposes; flattened 128-block x extent
__global__ void convT_qo(const float* __restrict__ qw, const float* __restrict__ ow,
                         ushort* __restrict__ qwt, ushort* __restrict__ owt) {
    int z = blockIdx.z, bx = blockIdx.x;
    if (z < EA) {
        int r0 = (bx & 31) * 32, c0 = (bx >> 5) * 32;      // 32x4 tiles of [1024][128]
        convT_body2<1024, 128>(qw + (size_t)z * 1024 * 128, qwt + (size_t)z * 128 * 1024, r0, c0);
    } else {
        int e = z - EA;
        int r0 = (bx & 3) * 32, c0 = (bx >> 2) * 32;       // 4x32 tiles of [128][1024]
        convT_body2<128, 1024>(ow + (size_t)e * 128 * 1024, owt + (size_t)e * 1024 * 128, r0, c0);
    }
}

// ---- qkv: merged kv (z<2) + q (z>=2, expert z-2) split-K MFMA, one dispatch ----------
__global__ __launch_bounds__(256) void qkv_mfma(
    const ushort* __restrict__ xnb, const ushort* __restrict__ kwt,
    const ushort* __restrict__ vwt, const ushort* __restrict__ qwt,
    const int* __restrict__ meta, const int* __restrict__ list,
    float* __restrict__ kpart, float* __restrict__ vpart, float* __restrict__ qpart) {
    int z = blockIdx.z;
    int m0 = blockIdx.x * 64;
    int s = blockIdx.y;
    int kbase = s * 512;
    __shared__ __align__(16) short As[2][64 * BSTR];
    __shared__ __align__(16) short Bs[2][128 * BSTR];
    int tid = threadIdx.x, w = tid >> 6, lane = tid & 63;
    int sr = lane >> 2, sc = (lane & 3) * 8;
    int wr = (w >> 1) * 32, wc = (w & 1) * 64;
    int m16 = lane & 15, q = lane >> 4;
    if (z < 2) {
        const ushort* W = z ? vwt : kwt;
        float* outp = z ? vpart : kpart;
        const ushort* ap = xnb + (size_t)(m0 + w * 16 + sr) * D + kbase + sc;
        const ushort* bp0 = W + (size_t)(w * 32 + sr) * D + kbase + sc;
        const ushort* bp1 = bp0 + (size_t)16 * D;
        f32x4 acc[2][4] = {};
        KLOOP(16, ap, bp0, bp1, 32)
#pragma unroll
        for (int i = 0; i < 2; i++)
#pragma unroll
            for (int r = 0; r < 4; r++) {
                int m = m0 + wr + i * 16 + q * 4 + r;
#pragma unroll
                for (int j = 0; j < 4; j++)
                    outp[((size_t)s * NTOK + m) * HD + wc + j * 16 + m16] = acc[i][j][r];
            }
    } else {
        int e = z - 2;
        int o = meta[96 + e], c = meta[97 + e] - o;
        if (m0 >= c) return;
        int ri = o + m0 + w * 16 + sr; if (ri > NPAIR - 1) ri = NPAIR - 1;
        const ushort* ap = xnb + (size_t)(list[ri] >> 1) * D + kbase + sc;
        const ushort* bp0 = qwt + (size_t)e * HD * D + (size_t)(w * 32 + sr) * D + kbase + sc;
        const ushort* bp1 = bp0 + (size_t)16 * D;
        f32x4 acc[2][4] = {};
        KLOOP(16, ap, bp0, bp1, 32)
#pragma unroll
        for (int i = 0; i < 2; i++)
#pragma unroll
            for (int r = 0; r < 4; r++) {
                int pos = o + m0 + wr + i * 16 + q * 4 + r;
                if (pos < o + c) {
#pragma unroll
                    for (int j = 0; j < 4; j++)
                        qpart[((size_t)s * NPAD + pos) * HD + wc + j * 16 + m16] = acc[i][j][r];
                }
            }
    }
}

// ---- merged reduce: blocks [0,NTOK) = kv path; [NTOK, NTOK+NPAIR) = q path ----------
__global__ void qkv_reduce(const float* __restrict__ kpart, const float* __restrict__ vpart,
                           const float* __restrict__ kb, const float* __restrict__ vb,
                           ushort* __restrict__ kb16, float* __restrict__ vbf,
                           const float* __restrict__ qpart, const float* __restrict__ qb,
                           const int* __restrict__ aidx, const int* __restrict__ list,
                           ushort* __restrict__ Qg) {
    int h = threadIdx.x;  // 128
    if (blockIdx.x < NTOK) {
        int t = blockIdx.x;
        float ka = kb[h], va = vb[h];
#pragma unroll
        for (int s = 0; s < NSPL; s++) {
            ka += kpart[((size_t)s * NTOK + t) * HD + h];
            va += vpart[((size_t)s * NTOK + t) * HD + h];
        }
        kb16[(size_t)t * HD + h] = f2b(ka);
        vbf[(size_t)t * HD + h] = va;
    } else {
        int pos = blockIdx.x - NTOK;
        int e = aidx[list[pos]];
        float a = qb[e * HD + h];
#pragma unroll
        for (int s = 0; s < NSPL; s++) a += qpart[((size_t)s * NPAD + pos) * HD + h];
        Qg[(size_t)pos * HD + h] = f2b(a * QSCALE);
    }
}

// ---------------- rel: MFMA GEMM  R[pos][r] = Qg[pos] . rel[r] ----------------
__global__ __launch_bounds__(256) void rel_mfma(
    const ushort* __restrict__ Qg, const ushort* __restrict__ relb,
    float* __restrict__ R) {
    int m0 = blockIdx.x * 64;
    int n0 = blockIdx.y * 128;
    __shared__ __align__(16) short As[2][64 * BSTR];
    __shared__ __align__(16) short Bs[2][128 * BSTR];
    int tid = threadIdx.x, w = tid >> 6, lane = tid & 63;
    int sr = lane >> 2, sc = (lane & 3) * 8;
    const ushort* ap = Qg + (size_t)(m0 + w * 16 + sr) * HD + sc;
    int r0 = n0 + w * 32 + sr;      if (r0 > RNUM - 1) r0 = RNUM - 1;
    int r1 = n0 + w * 32 + 16 + sr; if (r1 > RNUM - 1) r1 = RNUM - 1;
    const ushort* bp0 = relb + (size_t)r0 * HD + sc;
    const ushort* bp1 = relb + (size_t)r1 * HD + sc;
    int wr = (w >> 1) * 32, wc = (w & 1) * 64;
    int m16 = lane & 15, q = lane >> 4;
    f32x4 acc[2][4] = {};
    KLOOP(4, ap, bp0, bp1, 32)
#pragma unroll
    for (int i = 0; i < 2; i++)
#pragma unroll
        for (int r = 0; r < 4; r++) {
            int pos = m0 + wr + i * 16 + q * 4 + r;
#pragma unroll
            for (int j = 0; j < 4; j++) {
                int n = n0 + wc + j * 16 + m16;
                if (n < RNUM) R[(size_t)pos * RSTRIDE + n] = acc[i][j][r];
            }
        }
}

// ---------------- flash attention, KV-split: each block does 2 of 8 K/V tiles ---------
__global__ __launch_bounds__(256) void flash_attn(
    const ushort* __restrict__ Qg, const ushort* __restrict__ kb16,
    const ushort* __restrict__ vt16, const float* __restrict__ Rbuf,
    const int* __restrict__ meta, const int* __restrict__ list,
    float* __restrict__ Opart, float* __restrict__ mbuf, float* __restrict__ lbuf) {
    int bin = blockIdx.z;
    int o = meta[32 + bin], c = meta[bin];
    int m0 = blockIdx.x * 64;
    if (m0 >= c) return;
    int b = bin & 3;
    int half = blockIdx.y;              // 0..NKV-1
    int TK0 = half * (8 / NKV);         // first K-tile index of this split
    __shared__ __align__(16) ushort QP[64 * 128];       // Q tile, then P tile (wave-private rows)
    __shared__ __align__(16) ushort KV[2][128 * 128];   // [0]=K tile, [1]=V^T tile
    int tid = threadIdx.x, w = tid >> 6, lane = tid & 63;
    int m16 = lane & 15, q = lane >> 4;
    int srow4 = lane >> 4, scol = lane & 15;            // staging: 4 rows x 256B per 1KB issue

#pragma unroll
    for (int t = 0; t < 4; t++) {
        int row = w * 16 + t * 4 + srow4;
        int rg = o + m0 + row; if (rg > NPAIR - 1) rg = NPAIR - 1;   // poison guard
        gll(Qg + (size_t)rg * HD + ((scol ^ (row & 7)) * 8), &QP[(w * 16 + t * 4) * 128]);
    }
#pragma unroll
    for (int u = 0; u < 8; u++) {
        int row = w * 32 + u * 4 + srow4;
        gll(kb16 + ((size_t)b * SEQ + TK0 * 128 + row) * HD + ((scol ^ (row & 7)) * 8),
            &KV[0][(w * 32 + u * 4) * 128]);
    }
#pragma unroll
    for (int u = 0; u < 8; u++) {
        int row = w * 32 + u * 4 + srow4;
        gll(vt16 + ((size_t)b * HD + row) * SEQ + TK0 * 128 + ((scol ^ (row & 7)) * 8),
            &KV[1][(w * 32 + u * 4) * 128]);
    }

    int qpos[4]; const float* Rrow[4];
#pragma unroll
    for (int r = 0; r < 4; r++) {
        int pos = o + m0 + w * 16 + q * 4 + r;
        int pc = pos < NPAIR ? pos : NPAIR - 1;
        qpos[r] = (list[pc] >> 1) & (SEQ - 1);
        Rrow[r] = Rbuf + (size_t)pc * RSTRIDE;
    }
    float m_run[4], l_run[4];
#pragma unroll
    for (int r = 0; r < 4; r++) { m_run[r] = -1e30f; l_run[r] = 0.f; }
    f32x4 acc_o[8];
#pragma unroll
    for (int j = 0; j < 8; j++) acc_o[j] = (f32x4){0.f, 0.f, 0.f, 0.f};

    wait_vm16();   // own-wave Q staged (Q rows are wave-private; no barrier needed)
    bf16x8 qf[4];
#pragma unroll
    for (int kk = 0; kk < 4; kk++)
        qf[kk] = *(const bf16x8*)&QP[(w * 16 + m16) * 128 + (((q + 4 * kk) ^ (m16 & 7)) * 8)];

#pragma unroll
    for (int t2 = 0; t2 < 8 / NKV; t2++) {
        int kt = TK0 + t2;
        wait_vm8();          // own-wave K_kt done (V_kt may be in flight)
        bar();               // all waves' K tile present
        f32x4 s_[8];
#pragma unroll
        for (int j = 0; j < 8; j++) s_[j] = (f32x4){0.f, 0.f, 0.f, 0.f};
#pragma unroll
        for (int kk = 0; kk < 4; kk++) {
#pragma unroll
            for (int j = 0; j < 8; j++) {
                bf16x8 bb = *(const bf16x8*)&KV[0][(j * 16 + m16) * 128 + (((q + 4 * kk) ^ (m16 & 7)) * 8)];
                s_[j] = __builtin_amdgcn_mfma_f32_16x16x32_bf16(qf[kk], bb, s_[j], 0, 0, 0);
            }
        }
        float mloc[4] = {-1e30f, -1e30f, -1e30f, -1e30f};
#pragma unroll
        for (int j = 0; j < 8; j++) {
            int key = kt * 128 + j * 16 + m16;
#pragma unroll
            for (int r = 0; r < 4; r++) {
                int rix = key - qpos[r];
                rix = (rix < -MAXPOS ? -MAXPOS : (rix > MAXPOS ? MAXPOS : rix)) + MAXPOS;
                float vv = s_[j][r] + Rrow[r][rix];
                s_[j][r] = vv;
                mloc[r] = fmaxf(mloc[r], vv);
            }
        }
#pragma unroll
        for (int off = 8; off; off >>= 1)
#pragma unroll
            for (int r = 0; r < 4; r++) mloc[r] = fmaxf(mloc[r], __shfl_xor(mloc[r], off, 16));
        float scale_[4], lloc[4] = {0.f, 0.f, 0.f, 0.f};
#pragma unroll
        for (int r = 0; r < 4; r++) {
            float mn = fmaxf(m_run[r], mloc[r]);
            scale_[r] = __expf(m_run[r] - mn);
            m_run[r] = mn;
        }
#pragma unroll
        for (int j = 0; j < 8; j++) {
#pragma unroll
            for (int r = 0; r < 4; r++) {
                float p = __expf(s_[j][r] - m_run[r]);
                lloc[r] += p;
                int row = q * 4 + r;
                QP[(w * 16 + row) * 128 + ((j * 16 + m16) ^ ((row & 7) * 8))] = f2b(p);
            }
        }
#pragma unroll
        for (int off = 8; off; off >>= 1)
#pragma unroll
            for (int r = 0; r < 4; r++) lloc[r] += __shfl_xor(lloc[r], off, 16);
#pragma unroll
        for (int r = 0; r < 4; r++) l_run[r] = l_run[r] * scale_[r] + lloc[r];
#pragma unroll
        for (int j = 0; j < 8; j++)
#pragma unroll
            for (int r = 0; r < 4; r++) acc_o[j][r] *= scale_[r];
        bar();               // all waves done reading K tile
        if (t2 < 8 / NKV - 1) {
#pragma unroll
            for (int u = 0; u < 8; u++) {
                int row = w * 32 + u * 4 + srow4;
                gll(kb16 + ((size_t)b * SEQ + (kt + 1) * 128 + row) * HD + ((scol ^ (row & 7)) * 8),
                    &KV[0][(w * 32 + u * 4) * 128]);
            }
            wait_vm8();      // own-wave V_kt done (older than K_{kt+1} just issued)
        } else {
            wait_vm0();
        }
        bar();               // all waves' V tile present
#pragma unroll
        for (int kk = 0; kk < 4; kk++) {
            bf16x8 pf = *(const bf16x8*)&QP[(w * 16 + m16) * 128 + (((q + 4 * kk) ^ (m16 & 7)) * 8)];
#pragma unroll
            for (int j = 0; j < 8; j++) {
                bf16x8 vv = *(const bf16x8*)&KV[1][(j * 16 + m16) * 128 + (((q + 4 * kk) ^ (m16 & 7)) * 8)];
                acc_o[j] = __builtin_amdgcn_mfma_f32_16x16x32_bf16(pf, vv, acc_o[j], 0, 0, 0);
            }
        }
        bar();               // all waves done reading V tile
        if (t2 < 8 / NKV - 1) {
#pragma unroll
            for (int u = 0; u < 8; u++) {
                int row = w * 32 + u * 4 + srow4;
                gll(vt16 + ((size_t)b * HD + row) * SEQ + (kt + 1) * 128 + ((scol ^ (row & 7)) * 8),
                    &KV[1][(w * 32 + u * 4) * 128]);
            }
        }
    }
#pragma unroll
    for (int r = 0; r < 4; r++) {
        int pos = o + m0 + w * 16 + q * 4 + r;
        if (pos < o + c) {
            if (m16 == 0) {
                mbuf[(size_t)half * NPAD + pos] = m_run[r];
                lbuf[(size_t)half * NPAD + pos] = l_run[r];
            }
#pragma unroll
            for (int j = 0; j < 8; j++)
                Opart[((size_t)half * NPAD + pos) * HD + j * 16 + m16] = acc_o[j][r];
        }
    }
}

// ---------------- flash combine: merge NKV partials, apply gate, write bf16 ctx -------
__global__ void flash_combine(const float* __restrict__ Opart, const float* __restrict__ mbuf,
                              const float* __restrict__ lbuf, const float* __restrict__ aga,
                              const int* __restrict__ list, ushort* __restrict__ ctx16) {
    int pos = blockIdx.x, h = threadIdx.x;  // 128
    float M = -1e30f;
#pragma unroll
    for (int i = 0; i < NKV; i++) M = fmaxf(M, mbuf[(size_t)i * NPAD + pos]);
    float L = 0.f, O = 0.f;
#pragma unroll
    for (int i = 0; i < NKV; i++) {
        float e = __expf(mbuf[(size_t)i * NPAD + pos] - M);
        L += lbuf[(size_t)i * NPAD + pos] * e;
        O += Opart[((size_t)i * NPAD + pos) * HD + h] * e;
    }
    float g = aga[list[pos]] / L;
    ctx16[(size_t)pos * HD + h] = f2b(O * g);
}

// ---------------- o: MFMA ctx@o_w, dense bf16 per-pair rows ----------------
__global__ __launch_bounds__(256) void o_mfma(
    const ushort* __restrict__ ctx16, const ushort* __restrict__ owt,
    const int* __restrict__ meta, ushort* __restrict__ Ofb) {
    int e = blockIdx.z;
    int o = meta[96 + e], c = meta[97 + e] - o;
    int m0 = blockIdx.x * 64;
    if (m0 >= c) return;
    int n0 = blockIdx.y * 128;
    __shared__ __align__(16) short As[2][64 * BSTR];
    __shared__ __align__(16) short Bs[2][128 * BSTR];
    int tid = threadIdx.x, w = tid >> 6, lane = tid & 63;
    int sr = lane >> 2, sc = (lane & 3) * 8;
    int ar = o + m0 + w * 16 + sr; if (ar > NPAIR - 1) ar = NPAIR - 1;   // poison guard
    const ushort* ap = ctx16 + (size_t)ar * HD + sc;
    const ushort* bp0 = owt + (size_t)e * D * HD + (size_t)(n0 + w * 32 + sr) * HD + sc;
    const ushort* bp1 = bp0 + (size_t)16 * HD;
    int wr = (w >> 1) * 32, wc = (w & 1) * 64;
    int m16 = lane & 15, q = lane >> 4;
    f32x4 acc[2][4] = {};
    KLOOP(4, ap, bp0, bp1, 32)
#pragma unroll
    for (int i = 0; i < 2; i++)
#pragma unroll
        for (int r = 0; r < 4; r++) {
            int pos = o + m0 + wr + i * 16 + q * 4 + r;
            if (pos < o + c) {
#pragma unroll
                for (int j = 0; j < 4; j++)
                    Ofb[(size_t)pos * D + n0 + wc + j * 16 + m16] = f2b(acc[i][j][r]);
            }
        }
}

// ---------------- FFN GEMM1: Hb = g*relu(xn2 @ W1 + b1) ----------------
__global__ __launch_bounds__(256) void ffn_mfma1(
    const ushort* __restrict__ xnb2, const ushort* __restrict__ w1t,
    const float* __restrict__ b1, const int* __restrict__ meta,
    const int* __restrict__ list, const float* __restrict__ fga,
    ushort* __restrict__ Hb) {
    int e = blockIdx.z;
    int o = meta[16 + e], c = meta[e];
    int m0 = blockIdx.x * 64;
    if (m0 >= c) return;
    int n0 = blockIdx.y * 128;
    __shared__ __align__(16) short As[2][64 * BSTR];
    __shared__ __align__(16) short Bs[2][128 * BSTR];
    int tid = threadIdx.x, w = tid >> 6, lane = tid & 63;
    int sr = lane >> 2, sc = (lane & 3) * 8;
    int ri = o + m0 + w * 16 + sr; if (ri > NPAIR - 1) ri = NPAIR - 1;
    const ushort* ap = xnb2 + (size_t)(list[ri] >> 1) * D + sc;
    const ushort* bp0 = w1t + ((size_t)e * FH + n0 + w * 32 + sr) * D + sc;
    const ushort* bp1 = bp0 + (size_t)16 * D;
    int wr = (w >> 1) * 32, wc = (w & 1) * 64;
    int m16 = lane & 15, q = lane >> 4;
    f32x4 acc[2][4] = {};
    KLOOP(32, ap, bp0, bp1, 32)
#pragma unroll
    for (int i = 0; i < 2; i++)
#pragma unroll
        for (int r = 0; r < 4; r++) {
            int pos = o + m0 + wr + i * 16 + q * 4 + r;
            if (pos < o + c) {
                float g = fga[list[pos]];
#pragma unroll
                for (int j = 0; j < 4; j++) {
                    int n = n0 + wc + j * 16 + m16;
                    Hb[(size_t)pos * FH + n] = f2b(g * fmaxf(acc[i][j][r] + b1[e * FH + n], 0.f));
                }
            }
        }
}

// ---------------- FFN GEMM2: Of2b[pos] = Hb @ W2 (dense bf16 rows) ----------------
__global__ __launch_bounds__(256) void ffn_mfma2(
    const ushort* __restrict__ Hb, const ushort* __restrict__ w2t,
    const int* __restrict__ meta, ushort* __restrict__ Of2b) {
    int e = blockIdx.z;
    int o = meta[16 + e], c = meta[e];
    int m0 = blockIdx.x * 64;
    if (m0 >= c) return;
    int n0 = blockIdx.y * 128;
    __shared__ __align__(16) short As[2][64 * BSTR];
    __shared__ __align__(16) short Bs[2][128 * BSTR];
    int tid = threadIdx.x, w = tid >> 6, lane = tid & 63;
    int sr = lane >> 2, sc = (lane & 3) * 8;
    int ar = o + m0 + w * 16 + sr; if (ar > NPAIR - 1) ar = NPAIR - 1;   // poison guard
    const ushort* ap = Hb + (size_t)ar * FH + sc;
    const ushort* bp0 = w2t + ((size_t)e * D + n0 + w * 32 + sr) * FH + sc;
    const ushort* bp1 = bp0 + (size_t)16 * FH;
    int wr = (w >> 1) * 32, wc = (w & 1) * 64;
    int m16 = lane & 15, q = lane >> 4;
    f32x4 acc[2][4] = {};
    KLOOP(16, ap, bp0, bp1, 32)
#pragma unroll
    for (int i = 0; i < 2; i++)
#pragma unroll
        for (int r = 0; r < 4; r++) {
            int pos = o + m0 + wr + i * 16 + q * 4 + r;
            if (pos < o + c) {
#pragma unroll
                for (int j = 0; j < 4; j++)
                    Of2b[(size_t)pos * D + n0 + wc + j * 16 + m16] = f2b(acc[i][j][r]);
            }
        }
}

// ---------------- FFN combine ----------------
__global__ void ffn_combine(const float* __restrict__ x1, const float* __restrict__ b2,
                            const int* __restrict__ fidx, const float* __restrict__ fga,
                            const int* __restrict__ finv, const ushort* __restrict__ Of2b,
                            float* __restrict__ out) {
    int t = blockIdx.x, tid = threadIdx.x;
    int e0 = fidx[t * 2], e1 = fidx[t * 2 + 1];
    float g0 = fga[t * 2], g1 = fga[t * 2 + 1];
    int p0 = finv[t * 2], p1 = finv[t * 2 + 1];
#pragma unroll
    for (int i = 0; i < 4; i++) {
        int d = tid + i * 256;
        out[(size_t)t * D + d] = x1[(size_t)t * D + d]
                               + g0 * b2[e0 * D + d] + g1 * b2[e1 * D + d]
                               + b2f(Of2b[(size_t)p0 * D + d]) + b2f(Of2b[(size_t)p1 * D + d]);
    }
}

extern "C" void kernel_launch(void* const* d_in, const int* in_sizes, int n_in,
                              void* d_out, int out_size, void* d_ws, size_t ws_size,
                              hipStream_t stream) {
    const float* src   = (const float*)d_in[0];
    const float* ln1_w = (const float*)d_in[1];
    const float* ln1_b = (const float*)d_in[2];
    const float* ln2_w = (const float*)d_in[3];
    const float* ln2_b = (const float*)d_in[4];
    const float* agw   = (const float*)d_in[5];
    const float* qw    = (const float*)d_in[6];
    const float* qb    = (const float*)d_in[7];
    const float* kw    = (const float*)d_in[8];
    const float* kb    = (const float*)d_in[9];
    const float* vw    = (const float*)d_in[10];
    const float* vb    = (const float*)d_in[11];
    const float* ow    = (const float*)d_in[12];
    const float* ob    = (const float*)d_in[13];
    const float* rel   = (const float*)d_in[14];
    const float* fgw   = (const float*)d_in[15];
    const float* w1    = (const float*)d_in[16];
    const float* b1    = (const float*)d_in[17];
    const float* w2    = (const float*)d_in[18];
    const float* b2    = (const float*)d_in[19];
    float* out = (float*)d_out;

    char* p = (char*)d_ws;
    float* xn1  = (float*)p; p += (size_t)NTOK * D * 4;               // (unused slot, layout stability)
    float* x1   = (float*)p; p += (size_t)NTOK * D * 4;
    char*  sreg = p;         p += (size_t)NPAD * SEQ * 4;             // 34.1 MB
    ushort* Ofb  = (ushort*)sreg;                                     // attn: o rows (17 MB)
    ushort* w1t  = (ushort*)sreg;                                     // FFN: 16.78 MB
    ushort* w2t  = (ushort*)(sreg + (size_t)16777216);                // FFN: 16.78 MB
    char*  reg  = p;         p += (size_t)NPAD * 128 * 6 + (size_t)NPAIR * RSTRIDE * 4;
    ushort* ctx16 = (ushort*)reg;                                     // bf16 ctx (2.13 MB slot)
    ushort* Qg   = (ushort*)(reg + (size_t)NPAD * 128 * 4);           // 2.13 MB
    float*  Rbuf = (float*)(reg + (size_t)NPAD * 128 * 6);            // 4.33 MB
    ushort* Hb   = (ushort*)reg;                                      // FFN hidden (8.52 MB)
    char*  arena = p;        p += (size_t)4 * NPAD * 128 * 4;         // 17.04 MB
    float*  kpart = (float*)arena;
    float*  vpart = (float*)(arena + (size_t)NSPL * NTOK * HD * 4);
    float*  qpart = (float*)(arena + (size_t)2 * NSPL * NTOK * HD * 4);
    float*  Opart = (float*)arena;                                    // flash partials (NKV*NPAD*HD f32)
    ushort* Of2b  = (ushort*)arena;
    ushort* kb16 = (ushort*)p; p += (size_t)NTOK * HD * 2;
    float* vbf  = (float*)p; p += (size_t)NTOK * HD * 4;
    ushort* vt16 = (ushort*)p; p += (size_t)NTOK * HD * 2;
    ushort* kwt = (ushort*)p; p += (size_t)HD * D * 2;
    ushort* vwt = (ushort*)p; p += (size_t)HD * D * 2;
    ushort* qwt = (ushort*)p; p += (size_t)EA * HD * D * 2;
    ushort* owt = (ushort*)p; p += (size_t)EA * D * HD * 2;
    ushort* relb = (ushort*)p; p += (size_t)RNUM * HD * 2 + 256;
    int*   aidx = (int*)p;   p += NPAIR * 4;
    float* aga  = (float*)p; p += NPAIR * 4;
    int*   fidx = (int*)p;   p += NPAIR * 4;
    float* fga  = (float*)p; p += NPAIR * 4;
    int*   ameta = (int*)p;  p += 128 * 4;
    int*   alist = (int*)p;  p += NPAIR * 4;
    int*   ainv = (int*)p;   p += NPAIR * 4;
    int*   fmeta = (int*)p;  p += 64 * 4;
    int*   flist = (int*)p;  p += NPAIR * 4;
    int*   finv = (int*)p;   p += NPAIR * 4;
    ushort* xnb = (ushort*)p; p += (size_t)NTOK * D * 2;              // bf16 LN out (GEMM A operand)
    float* mbuf = (float*)p; p += (size_t)NKV * NPAD * 4;             // flash row-max stats
    float* lbuf = (float*)p; p += (size_t)NKV * NPAD * 4;             // flash row-sum stats
    (void)xn1;

    // ---- attention ----
    zero_meta<<<1, 128, 0, stream>>>(ameta, fmeta);
    ln_router_kernel<EA><<<NTOK, 256, 0, stream>>>(src, ln1_w, ln1_b, agw, xnb, aidx, aga);
    abin_count<<<NPAIR / 256, 256, 0, stream>>>(aidx, ameta);
    abin_scan<<<1, 64, 0, stream>>>(ameta);
    abin_scatter<<<NPAIR / 256, 256, 0, stream>>>(aidx, ameta, alist, ainv);
    convT_kv<<<dim3(32, 4, 3), 256, 0, stream>>>(kw, vw, rel, kwt, vwt, relb);
    convT_qo<<<dim3(128, 1, 2 * EA), 256, 0, stream>>>(qw, ow, qwt, owt);
    qkv_mfma<<<dim3(64, NSPL, 2 + EA), 256, 0, stream>>>(xnb, kwt, vwt, qwt, ameta, alist,
                                                          kpart, vpart, qpart);
    qkv_reduce<<<NTOK + NPAIR, 128, 0, stream>>>(kpart, vpart, kb, vb, kb16, vbf,
                                                 qpart, qb, aidx, alist, Qg);
    convT_kernel<1024, 128><<<dim3(32, 4, 4), 256, 0, stream>>>(vbf, vt16);
    rel_mfma<<<dim3(NPAIR / 64, 2), 256, 0, stream>>>(Qg, relb, Rbuf);
    flash_attn<<<dim3(12, NKV, 32), 256, 0, stream>>>(Qg, kb16, vt16, Rbuf, ameta, alist,
                                                      Opart, mbuf, lbuf);
    flash_combine<<<NPAIR, 128, 0, stream>>>(Opart, mbuf, lbuf, aga, alist, ctx16);
    o_mfma<<<dim3(40, 8, EA), 256, 0, stream>>>(ctx16, owt, ameta, Ofb);
    attn_ln_router<EF><<<NTOK, 256, 0, stream>>>(src, ob, aidx, aga, ainv, Ofb,
                                                 ln2_w, ln2_b, fgw, x1, xnb, fidx, fga);

    // ---- FFN ----
    bin_count<<<NPAIR / 256, 256, 0, stream>>>(fidx, fmeta);
    bin_scan<<<1, 64, 0, stream>>>(fmeta);
    bin_scatter<<<NPAIR / 256, 256, 0, stream>>>(fidx, fmeta, flist, finv);
    convT_kernel<1024, 512><<<dim3(32, 16, EF), 256, 0, stream>>>(w1, w1t);
    convT_kernel<512, 1024><<<dim3(16, 32, EF), 256, 0, stream>>>(w2, w2t);
    ffn_mfma1<<<dim3(20, 4, EF), 256, 0, stream>>>(xnb, w1t, b1, fmeta, flist, fga, Hb);
    ffn_mfma2<<<dim3(20, 8, EF), 256, 0, stream>>>(Hb, w2t, fmeta, Of2b);
    ffn_combine<<<NTOK, 256, 0, stream>>>(x1, b2, fidx, fga, finv, Of2b, out);
}